// Round 2
// baseline (838.182 us; speedup 1.0000x reference)
//
#include <hip/hip_runtime.h>
#include <cstdint>

#define DIM 768
#define SEQ 2048
#define NB 2
#define NH 16
#define HD 48
#define NROWS (NB*SEQ)   // 4096

// ---------------------------------------------------------------------------
// GEMM: C = A * B^T.  A [M,K] row-major, B [N,K] row-major (torch Linear W).
// Tiles 128x128, K-step 16. 256 threads, 8x8 micro-tile per thread.
// blockIdx.z selects among 3 (B,C) pairs so QKV runs as one launch.
// ---------------------------------------------------------------------------
__global__ __launch_bounds__(256)
void gemm128(const float* __restrict__ A,
             const float* __restrict__ B0,
             const float* __restrict__ B1,
             const float* __restrict__ B2,
             float* __restrict__ C0,
             float* __restrict__ C1,
             float* __restrict__ C2)
{
    const float* B = B0; float* C = C0;
    if (blockIdx.z == 1) { B = B1; C = C1; }
    else if (blockIdx.z == 2) { B = B2; C = C2; }

    // k-major LDS tiles; pad 132 so transposed stores are ~2-way max and
    // rows stay 16B-aligned for float4 reads (132 % 4 == 0).
    __shared__ float As[16][132];
    __shared__ float Bs[16][132];

    const int tid = threadIdx.x;
    const int tx = tid & 15, ty = tid >> 4;
    const int m0 = blockIdx.y * 128;
    const int n0 = blockIdx.x * 128;

    // staging: 4 lanes per row cover 16 k as float4s; 64 rows per pass, 2 passes
    const int lk = (tid & 3) * 4;   // 0,4,8,12
    const int lm = tid >> 2;        // 0..63

    const float* Ap = A + (size_t)(m0 + lm) * DIM + lk;
    const float* Bp = B + (size_t)(n0 + lm) * DIM + lk;

    float acc[8][8];
#pragma unroll
    for (int i = 0; i < 8; ++i)
#pragma unroll
        for (int j = 0; j < 8; ++j) acc[i][j] = 0.f;

    for (int k0 = 0; k0 < DIM; k0 += 16) {
        // issue global loads before the barrier (latency overlaps the wait)
        float4 a0 = *(const float4*)(Ap + k0);
        float4 a1 = *(const float4*)(Ap + k0 + (size_t)64 * DIM);
        float4 b0 = *(const float4*)(Bp + k0);
        float4 b1 = *(const float4*)(Bp + k0 + (size_t)64 * DIM);
        __syncthreads();   // previous iteration's compute done before overwrite
        As[lk+0][lm]    = a0.x; As[lk+1][lm]    = a0.y; As[lk+2][lm]    = a0.z; As[lk+3][lm]    = a0.w;
        As[lk+0][lm+64] = a1.x; As[lk+1][lm+64] = a1.y; As[lk+2][lm+64] = a1.z; As[lk+3][lm+64] = a1.w;
        Bs[lk+0][lm]    = b0.x; Bs[lk+1][lm]    = b0.y; Bs[lk+2][lm]    = b0.z; Bs[lk+3][lm]    = b0.w;
        Bs[lk+0][lm+64] = b1.x; Bs[lk+1][lm+64] = b1.y; Bs[lk+2][lm+64] = b1.z; Bs[lk+3][lm+64] = b1.w;
        __syncthreads();
#pragma unroll
        for (int k = 0; k < 16; ++k) {
            float4 av0 = *(const float4*)&As[k][ty*8];
            float4 av1 = *(const float4*)&As[k][ty*8+4];
            float4 bv0 = *(const float4*)&Bs[k][tx*8];
            float4 bv1 = *(const float4*)&Bs[k][tx*8+4];
            float ar[8] = {av0.x,av0.y,av0.z,av0.w,av1.x,av1.y,av1.z,av1.w};
            float br[8] = {bv0.x,bv0.y,bv0.z,bv0.w,bv1.x,bv1.y,bv1.z,bv1.w};
#pragma unroll
            for (int i = 0; i < 8; ++i)
#pragma unroll
                for (int j = 0; j < 8; ++j)
                    acc[i][j] = fmaf(ar[i], br[j], acc[i][j]);
        }
    }
#pragma unroll
    for (int i = 0; i < 8; ++i) {
        float* Crow = C + (size_t)(m0 + ty*8 + i) * DIM + n0 + tx*8;
        float4 c0 = {acc[i][0],acc[i][1],acc[i][2],acc[i][3]};
        float4 c1 = {acc[i][4],acc[i][5],acc[i][6],acc[i][7]};
        *(float4*)(Crow)   = c0;
        *(float4*)(Crow+4) = c1;
    }
}

// ---------------------------------------------------------------------------
// Flash attention, fp32. One block per (q-tile of 64 rows, head, batch).
// 256 threads as 16x16: score micro 4x4 (rows ty*4+i, cols tx*4+j),
// PV micro 4 rows x 3 dims (dims tx*3+dd). Row stats shared across the
// 16-lane tx-group via __shfl_xor, so m/l/alpha live replicated in regs.
// ---------------------------------------------------------------------------
__global__ __launch_bounds__(256)
void flash64(const float* __restrict__ Qm,
             const float* __restrict__ Km,
             const float* __restrict__ Vm,
             float* __restrict__ Om)
{
    const int qt  = blockIdx.x;   // 0..31
    const int h   = blockIdx.y;   // 0..15
    const int b   = blockIdx.z;   // 0..1
    const int tid = threadIdx.x;
    const int tx = tid & 15, ty = tid >> 4;

    __shared__ float Qs[48][68];  // [d][r]
    __shared__ float Ks[48][68];  // [d][c]
    __shared__ float Vs[64][52];  // [c][d]
    __shared__ float Ps[64][68];  // [c][r]  (P transposed)

    const int q0 = qt * 64;
    const size_t base = (size_t)b * SEQ * DIM + (size_t)h * HD;
    const float scale = 0.14433756729740643f;  // 48^-0.5

    for (int i = tid; i < 64*48; i += 256) {
        int r = i / 48, d = i - r * 48;
        Qs[d][r] = Qm[base + (size_t)(q0 + r) * DIM + d];
    }

    float m_i[4], l_i[4], o[4][3];
#pragma unroll
    for (int i = 0; i < 4; ++i) {
        m_i[i] = -1e30f; l_i[i] = 0.f;
        o[i][0] = 0.f; o[i][1] = 0.f; o[i][2] = 0.f;
    }

    for (int c0 = 0; c0 < SEQ; c0 += 64) {
        // prefetch K/V tile into regs before the barrier
        float kr[12], vr[12];
#pragma unroll
        for (int t = 0; t < 12; ++t) {
            int i = tid + t * 256;
            int r = i / 48, d = i - r * 48;
            size_t g = base + (size_t)(c0 + r) * DIM + d;
            kr[t] = Km[g];
            vr[t] = Vm[g];
        }
        __syncthreads();   // everyone done reading Ks/Vs/Ps of prev tile
#pragma unroll
        for (int t = 0; t < 12; ++t) {
            int i = tid + t * 256;
            int r = i / 48, d = i - r * 48;
            Ks[d][r] = kr[t];
            Vs[r][d] = vr[t];
        }
        __syncthreads();

        // S = (Q K^T) * scale, 4x4 per thread
        float s[4][4] = {};
#pragma unroll 8
        for (int d = 0; d < 48; ++d) {
            float4 qa = *(const float4*)&Qs[d][ty*4];
            float4 kb = *(const float4*)&Ks[d][tx*4];
            float qv[4] = {qa.x,qa.y,qa.z,qa.w};
            float kv[4] = {kb.x,kb.y,kb.z,kb.w};
#pragma unroll
            for (int i = 0; i < 4; ++i)
#pragma unroll
                for (int j = 0; j < 4; ++j)
                    s[i][j] = fmaf(qv[i], kv[j], s[i][j]);
        }
#pragma unroll
        for (int i = 0; i < 4; ++i)
#pragma unroll
            for (int j = 0; j < 4; ++j) s[i][j] *= scale;

        // row max across the 16-lane tx group
        float mx[4];
#pragma unroll
        for (int i = 0; i < 4; ++i)
            mx[i] = fmaxf(fmaxf(s[i][0], s[i][1]), fmaxf(s[i][2], s[i][3]));
#pragma unroll
        for (int off = 1; off < 16; off <<= 1) {
#pragma unroll
            for (int i = 0; i < 4; ++i)
                mx[i] = fmaxf(mx[i], __shfl_xor(mx[i], off));
        }

        float alpha[4], p[4][4], rs[4];
#pragma unroll
        for (int i = 0; i < 4; ++i) {
            float mn = fmaxf(m_i[i], mx[i]);
            alpha[i] = __expf(m_i[i] - mn);
            m_i[i] = mn;
            rs[i] = 0.f;
#pragma unroll
            for (int j = 0; j < 4; ++j) {
                p[i][j] = __expf(s[i][j] - mn);
                rs[i] += p[i][j];
            }
        }
#pragma unroll
        for (int off = 1; off < 16; off <<= 1) {
#pragma unroll
            for (int i = 0; i < 4; ++i)
                rs[i] += __shfl_xor(rs[i], off);
        }
#pragma unroll
        for (int i = 0; i < 4; ++i)
            l_i[i] = alpha[i] * l_i[i] + rs[i];

        // store P transposed: one float4 column per j
#pragma unroll
        for (int j = 0; j < 4; ++j) {
            float4 col = {p[0][j], p[1][j], p[2][j], p[3][j]};
            *(float4*)&Ps[tx*4+j][ty*4] = col;
        }
        __syncthreads();

        // O = alpha*O + P*V
#pragma unroll
        for (int i = 0; i < 4; ++i) {
            o[i][0] *= alpha[i]; o[i][1] *= alpha[i]; o[i][2] *= alpha[i];
        }
        const int d0 = tx * 3;
#pragma unroll 8
        for (int c = 0; c < 64; ++c) {
            float4 pc = *(const float4*)&Ps[c][ty*4];
            float v0 = Vs[c][d0+0], v1 = Vs[c][d0+1], v2 = Vs[c][d0+2];
            o[0][0] = fmaf(pc.x, v0, o[0][0]); o[0][1] = fmaf(pc.x, v1, o[0][1]); o[0][2] = fmaf(pc.x, v2, o[0][2]);
            o[1][0] = fmaf(pc.y, v0, o[1][0]); o[1][1] = fmaf(pc.y, v1, o[1][1]); o[1][2] = fmaf(pc.y, v2, o[1][2]);
            o[2][0] = fmaf(pc.z, v0, o[2][0]); o[2][1] = fmaf(pc.z, v1, o[2][1]); o[2][2] = fmaf(pc.z, v2, o[2][2]);
            o[3][0] = fmaf(pc.w, v0, o[3][0]); o[3][1] = fmaf(pc.w, v1, o[3][1]); o[3][2] = fmaf(pc.w, v2, o[3][2]);
        }
        // next iteration's first __syncthreads protects Ks/Vs/Ps reuse
    }

#pragma unroll
    for (int i = 0; i < 4; ++i) {
        float inv = 1.0f / l_i[i];
        size_t g = base + (size_t)(q0 + ty*4 + i) * DIM + tx*3;
        Om[g+0] = o[i][0] * inv;
        Om[g+1] = o[i][1] * inv;
        Om[g+2] = o[i][2] * inv;
    }
}

extern "C" void kernel_launch(void* const* d_in, const int* in_sizes, int n_in,
                              void* d_out, int out_size, void* d_ws, size_t ws_size,
                              hipStream_t stream)
{
    const float* x  = (const float*)d_in[0];
    const float* Wq = (const float*)d_in[1];
    const float* Wk = (const float*)d_in[2];
    const float* Wv = (const float*)d_in[3];
    const float* Wo = (const float*)d_in[4];
    float* out = (float*)d_out;

    float* q   = (float*)d_ws;                 // [4096][768]
    float* k   = q + (size_t)NROWS * DIM;
    float* v   = k + (size_t)NROWS * DIM;
    float* ctx = v + (size_t)NROWS * DIM;      // total 50.3 MB

    dim3 g1(DIM/128, NROWS/128, 3);
    gemm128<<<g1, 256, 0, stream>>>(x, Wq, Wk, Wv, q, k, v);

    dim3 g2(SEQ/64, NH, NB);
    flash64<<<g2, 256, 0, stream>>>(q, k, v, ctx);

    dim3 g3(DIM/128, NROWS/128, 1);
    gemm128<<<g3, 256, 0, stream>>>(ctx, Wo, Wo, Wo, out, out, out);
}

// Round 4
// 506.632 us; speedup vs baseline: 1.6544x; 1.6544x over previous
//
#include <hip/hip_runtime.h>
#include <cstdint>

#define DIM 768
#define SEQ 2048
#define NB 2
#define NH 16
#define HD 48
#define NROWS (NB*SEQ)   // 4096

typedef __attribute__((ext_vector_type(8))) short bf16x8;
typedef __attribute__((ext_vector_type(4))) float f32x4;

__device__ __forceinline__ short f2bf(float f) {
    union { float f; uint32_t u; } v; v.f = f;
    uint32_t u = v.u;
    uint32_t r = (u + 0x7FFFu + ((u >> 16) & 1u)) >> 16;
    return (short)r;
}

// ---------------------------------------------------------------------------
// GEMM: C = A * B^T, fp32 (unchanged from R2 verified version).
// ---------------------------------------------------------------------------
__global__ __launch_bounds__(256)
void gemm128(const float* __restrict__ A,
             const float* __restrict__ B0,
             const float* __restrict__ B1,
             const float* __restrict__ B2,
             float* __restrict__ C0,
             float* __restrict__ C1,
             float* __restrict__ C2)
{
    const float* B = B0; float* C = C0;
    if (blockIdx.z == 1) { B = B1; C = C1; }
    else if (blockIdx.z == 2) { B = B2; C = C2; }

    __shared__ float As[16][132];
    __shared__ float Bs[16][132];

    const int tid = threadIdx.x;
    const int tx = tid & 15, ty = tid >> 4;
    const int m0 = blockIdx.y * 128;
    const int n0 = blockIdx.x * 128;

    const int lk = (tid & 3) * 4;
    const int lm = tid >> 2;

    const float* Ap = A + (size_t)(m0 + lm) * DIM + lk;
    const float* Bp = B + (size_t)(n0 + lm) * DIM + lk;

    float acc[8][8];
#pragma unroll
    for (int i = 0; i < 8; ++i)
#pragma unroll
        for (int j = 0; j < 8; ++j) acc[i][j] = 0.f;

    for (int k0 = 0; k0 < DIM; k0 += 16) {
        float4 a0 = *(const float4*)(Ap + k0);
        float4 a1 = *(const float4*)(Ap + k0 + (size_t)64 * DIM);
        float4 b0 = *(const float4*)(Bp + k0);
        float4 b1 = *(const float4*)(Bp + k0 + (size_t)64 * DIM);
        __syncthreads();
        As[lk+0][lm]    = a0.x; As[lk+1][lm]    = a0.y; As[lk+2][lm]    = a0.z; As[lk+3][lm]    = a0.w;
        As[lk+0][lm+64] = a1.x; As[lk+1][lm+64] = a1.y; As[lk+2][lm+64] = a1.z; As[lk+3][lm+64] = a1.w;
        Bs[lk+0][lm]    = b0.x; Bs[lk+1][lm]    = b0.y; Bs[lk+2][lm]    = b0.z; Bs[lk+3][lm]    = b0.w;
        Bs[lk+0][lm+64] = b1.x; Bs[lk+1][lm+64] = b1.y; Bs[lk+2][lm+64] = b1.z; Bs[lk+3][lm+64] = b1.w;
        __syncthreads();
#pragma unroll
        for (int k = 0; k < 16; ++k) {
            float4 av0 = *(const float4*)&As[k][ty*8];
            float4 av1 = *(const float4*)&As[k][ty*8+4];
            float4 bv0 = *(const float4*)&Bs[k][tx*8];
            float4 bv1 = *(const float4*)&Bs[k][tx*8+4];
            float ar[8] = {av0.x,av0.y,av0.z,av0.w,av1.x,av1.y,av1.z,av1.w};
            float br[8] = {bv0.x,bv0.y,bv0.z,bv0.w,bv1.x,bv1.y,bv1.z,bv1.w};
#pragma unroll
            for (int i = 0; i < 8; ++i)
#pragma unroll
                for (int j = 0; j < 8; ++j)
                    acc[i][j] = fmaf(ar[i], br[j], acc[i][j]);
        }
    }
#pragma unroll
    for (int i = 0; i < 8; ++i) {
        float* Crow = C + (size_t)(m0 + ty*8 + i) * DIM + n0 + tx*8;
        float4 c0 = {acc[i][0],acc[i][1],acc[i][2],acc[i][3]};
        float4 c1 = {acc[i][4],acc[i][5],acc[i][6],acc[i][7]};
        *(float4*)(Crow)   = c0;
        *(float4*)(Crow+4) = c1;
    }
}

// ---------------------------------------------------------------------------
// Flash attention via bf16 MFMA (16x16x32). Block = 256 threads = 4 waves.
// Q-tile 64 rows (16/wave); KV tiles of 64. HD=48 padded to K=64 (2 MFMAs).
// LDS row stride 72 elems (144B = 36 words) -> b128 frag reads spread all
// 32 banks uniformly (conflict-free). P goes D-layout -> LDS -> A-layout.
// R4 fix: zero K_lds pad columns 48..63 — MFMA B-frags read them (t=1,
// kb>=2); uninitialized LDS there decoded as NaN/Inf and 0*NaN = NaN.
// ---------------------------------------------------------------------------
__global__ __launch_bounds__(256)
void flash_mfma(const float* __restrict__ Qm,
                const float* __restrict__ Km,
                const float* __restrict__ Vm,
                float* __restrict__ Om)
{
    __shared__ short K_lds[64 * 72];       // [c][d] bf16
    __shared__ short Vt_lds[48 * 72];      // [d][c] bf16
    __shared__ short P_lds[4][16 * 72];    // per wave: [q][c] bf16

    const int qt  = blockIdx.x;   // 0..31
    const int h   = blockIdx.y;
    const int b   = blockIdx.z;
    const int tid = threadIdx.x;
    const int wid  = tid >> 6;
    const int lane = tid & 63;
    const int m  = lane & 15;     // row-in-16 (A/D col group)
    const int kb = lane >> 4;     // 0..3 k-block

    const int q0 = qt * 64;
    const size_t base = (size_t)b * SEQ * DIM + (size_t)h * HD;
    const float scale = 0.14433756729740643f;  // 48^-0.5

    // zero the K_lds pad region d=48..63 once; staging never writes it,
    // so it stays zero for every KV tile.
    for (int i = tid; i < 64 * 16; i += 256) {
        int r = i >> 4, c = i & 15;
        K_lds[r * 72 + 48 + c] = 0;
    }

    // ---- Q fragments in registers (row = q0 + wid*16 + m) ----
    bf16x8 qf[2];
#pragma unroll
    for (int t = 0; t < 2; ++t) {
        int d0 = t * 32 + kb * 8;
        bf16x8 q8 = {};
        if (d0 < 48) {
            const float* g = Qm + base + (size_t)(q0 + wid*16 + m) * DIM + d0;
            float4 a = *(const float4*)g;
            float4 c = *(const float4*)(g + 4);
            q8[0]=f2bf(a.x); q8[1]=f2bf(a.y); q8[2]=f2bf(a.z); q8[3]=f2bf(a.w);
            q8[4]=f2bf(c.x); q8[5]=f2bf(c.y); q8[6]=f2bf(c.z); q8[7]=f2bf(c.w);
        }
        qf[t] = q8;
    }

    float m_i[4], l_i[4];
    f32x4 o[3];
#pragma unroll
    for (int r = 0; r < 4; ++r) { m_i[r] = -1e30f; l_i[r] = 0.f; }
#pragma unroll
    for (int ds = 0; ds < 3; ++ds) o[ds] = (f32x4){0.f,0.f,0.f,0.f};

    const float* Kg = Km + base;
    const float* Vg = Vm + base;

    for (int c0 = 0; c0 < SEQ; c0 += 64) {
        // -- stage K, V^T (fp32 global -> bf16 LDS) --
        float4 kr[3], vr[3];
        int rowv[3], dv[3];
#pragma unroll
        for (int i = 0; i < 3; ++i) {
            int idx = tid + i * 256;            // 0..767 float4-chunks
            int row = idx / 12;
            int dch = idx - row * 12;
            rowv[i] = row; dv[i] = dch * 4;
            const float* kp = Kg + (size_t)(c0 + row) * DIM + dv[i];
            const float* vp = Vg + (size_t)(c0 + row) * DIM + dv[i];
            kr[i] = *(const float4*)kp;
            vr[i] = *(const float4*)vp;
        }
        __syncthreads();   // prior tile's LDS reads complete
#pragma unroll
        for (int i = 0; i < 3; ++i) {
            short4 ks; ks.x=f2bf(kr[i].x); ks.y=f2bf(kr[i].y); ks.z=f2bf(kr[i].z); ks.w=f2bf(kr[i].w);
            *(short4*)&K_lds[rowv[i]*72 + dv[i]] = ks;
            Vt_lds[(dv[i]+0)*72 + rowv[i]] = f2bf(vr[i].x);
            Vt_lds[(dv[i]+1)*72 + rowv[i]] = f2bf(vr[i].y);
            Vt_lds[(dv[i]+2)*72 + rowv[i]] = f2bf(vr[i].z);
            Vt_lds[(dv[i]+3)*72 + rowv[i]] = f2bf(vr[i].w);
        }
        __syncthreads();

        // -- S = Q K^T (4 col-subtiles x 2 k-slices) --
        f32x4 s[4];
#pragma unroll
        for (int cs = 0; cs < 4; ++cs) {
            f32x4 acc = (f32x4){0.f,0.f,0.f,0.f};
#pragma unroll
            for (int t = 0; t < 2; ++t) {
                bf16x8 kf = *(bf16x8*)&K_lds[(cs*16 + m)*72 + t*32 + kb*8];
                acc = __builtin_amdgcn_mfma_f32_16x16x32_bf16(qf[t], kf, acc, 0, 0, 0);
            }
            s[cs] = acc;
        }

        // -- online softmax (rows (lane>>4)*4+r, cols cs*16+(lane&15)) --
        float mx[4], alpha[4], rs[4];
#pragma unroll
        for (int r = 0; r < 4; ++r) {
#pragma unroll
            for (int cs = 0; cs < 4; ++cs) s[cs][r] *= scale;
            mx[r] = fmaxf(fmaxf(s[0][r], s[1][r]), fmaxf(s[2][r], s[3][r]));
        }
#pragma unroll
        for (int off = 1; off < 16; off <<= 1)
#pragma unroll
            for (int r = 0; r < 4; ++r)
                mx[r] = fmaxf(mx[r], __shfl_xor(mx[r], off));
#pragma unroll
        for (int r = 0; r < 4; ++r) {
            float mn = fmaxf(m_i[r], mx[r]);
            alpha[r] = __expf(m_i[r] - mn);
            m_i[r] = mn;
            rs[r] = 0.f;
#pragma unroll
            for (int cs = 0; cs < 4; ++cs) {
                float p = __expf(s[cs][r] - mn);
                s[cs][r] = p;
                rs[r] += p;
            }
        }
#pragma unroll
        for (int off = 1; off < 16; off <<= 1)
#pragma unroll
            for (int r = 0; r < 4; ++r)
                rs[r] += __shfl_xor(rs[r], off);
#pragma unroll
        for (int r = 0; r < 4; ++r)
            l_i[r] = alpha[r] * l_i[r] + rs[r];

        // -- P (D-layout f32) -> LDS bf16 --
#pragma unroll
        for (int cs = 0; cs < 4; ++cs)
#pragma unroll
            for (int r = 0; r < 4; ++r)
                P_lds[wid][(kb*4 + r)*72 + cs*16 + m] = f2bf(s[cs][r]);

        // -- O = alpha*O + P V --
#pragma unroll
        for (int ds = 0; ds < 3; ++ds)
#pragma unroll
            for (int r = 0; r < 4; ++r)
                o[ds][r] *= alpha[r];

        bf16x8 pf[2];
#pragma unroll
        for (int t = 0; t < 2; ++t)
            pf[t] = *(bf16x8*)&P_lds[wid][m*72 + t*32 + kb*8];
#pragma unroll
        for (int ds = 0; ds < 3; ++ds) {
#pragma unroll
            for (int t = 0; t < 2; ++t) {
                bf16x8 vf = *(bf16x8*)&Vt_lds[(ds*16 + m)*72 + t*32 + kb*8];
                o[ds] = __builtin_amdgcn_mfma_f32_16x16x32_bf16(pf[t], vf, o[ds], 0, 0, 0);
            }
        }
    }

    float inv[4];
#pragma unroll
    for (int r = 0; r < 4; ++r) inv[r] = 1.0f / l_i[r];
#pragma unroll
    for (int ds = 0; ds < 3; ++ds)
#pragma unroll
        for (int r = 0; r < 4; ++r)
            Om[base + (size_t)(q0 + wid*16 + kb*4 + r) * DIM + ds*16 + m] = o[ds][r] * inv[r];
}

extern "C" void kernel_launch(void* const* d_in, const int* in_sizes, int n_in,
                              void* d_out, int out_size, void* d_ws, size_t ws_size,
                              hipStream_t stream)
{
    const float* x  = (const float*)d_in[0];
    const float* Wq = (const float*)d_in[1];
    const float* Wk = (const float*)d_in[2];
    const float* Wv = (const float*)d_in[3];
    const float* Wo = (const float*)d_in[4];
    float* out = (float*)d_out;

    float* q   = (float*)d_ws;                 // [4096][768] fp32
    float* k   = q + (size_t)NROWS * DIM;
    float* v   = k + (size_t)NROWS * DIM;
    float* ctx = v + (size_t)NROWS * DIM;      // total 50.3 MB

    dim3 g1(DIM/128, NROWS/128, 3);
    gemm128<<<g1, 256, 0, stream>>>(x, Wq, Wk, Wv, q, k, v);

    dim3 g2(SEQ/64, NH, NB);
    flash_mfma<<<g2, 256, 0, stream>>>(q, k, v, ctx);

    dim3 g3(DIM/128, NROWS/128, 1);
    gemm128<<<g3, 256, 0, stream>>>(ctx, Wo, Wo, Wo, out, out, out);
}

// Round 5
// 255.601 us; speedup vs baseline: 3.2793x; 1.9821x over previous
//
#include <hip/hip_runtime.h>
#include <cstdint>

#define DIM 768
#define SEQ 2048
#define NB 2
#define NH 16
#define HD 48
#define NROWS (NB*SEQ)   // 4096

typedef __attribute__((ext_vector_type(8))) short bf16x8;
typedef __attribute__((ext_vector_type(4))) float f32x4;

__device__ __forceinline__ short f2bf(float f) {
    union { float f; uint32_t u; } v; v.f = f;
    uint32_t u = v.u;
    uint32_t r = (u + 0x7FFFu + ((u >> 16) & 1u)) >> 16;
    return (short)r;
}

// ---------------------------------------------------------------------------
// fp32 -> bf16 pre-convert: dst = concat(xb, wqb, wkb, wvb, wob)
// ---------------------------------------------------------------------------
__global__ __launch_bounds__(256)
void cvt_bf16(const float* __restrict__ x,  const float* __restrict__ wq,
              const float* __restrict__ wk, const float* __restrict__ wv,
              const float* __restrict__ wo, short* __restrict__ dst)
{
    const int XN4 = (NROWS*DIM)/4;   // 786432
    const int WN4 = (DIM*DIM)/4;     // 147456
    const int T4  = XN4 + 4*WN4;     // 1376256
    for (int i = blockIdx.x*blockDim.x + threadIdx.x; i < T4; i += gridDim.x*blockDim.x) {
        const float* src; int off;
        if (i < XN4) { src = x; off = i; }
        else {
            int j = i - XN4;
            int w = j / WN4, r = j - w*WN4;
            src = (w==0) ? wq : (w==1) ? wk : (w==2) ? wv : wo;
            off = r;
        }
        float4 v = *(const float4*)(src + (size_t)off*4);
        short4 s; s.x=f2bf(v.x); s.y=f2bf(v.y); s.z=f2bf(v.z); s.w=f2bf(v.w);
        *(short4*)(dst + (size_t)i*4) = s;
    }
}

// ---------------------------------------------------------------------------
// bf16 MFMA GEMM: C = A * B^T. A [M][768] bf16, B [768][768] bf16 (Linear W).
// 128x128 tile, BK=64, 256 thr = 4 waves, each wave a 64x64 quadrant
// (4x4 frags of 16x16x32). LDS rows are 128 B; XOR swizzle slot^=(row&7)
// applied at BOTH stage-in (source addr) and frag read -> ~2-way max.
// F32OUT: fp32 C (final projection) vs bf16 C (q/k/v).
// ---------------------------------------------------------------------------
template<bool F32OUT>
__global__ __launch_bounds__(256)
void gemm_mfma(const short* __restrict__ A,
               const short* __restrict__ B0, const short* __restrict__ B1,
               const short* __restrict__ B2,
               void* __restrict__ C0v, void* __restrict__ C1v, void* __restrict__ C2v)
{
    const short* B = B0; void* Cv = C0v;
    if (blockIdx.z == 1) { B = B1; Cv = C1v; }
    else if (blockIdx.z == 2) { B = B2; Cv = C2v; }

    __shared__ short As[128*64];
    __shared__ short Bs[128*64];

    const int tid  = threadIdx.x;
    const int lane = tid & 63;
    const int wid  = tid >> 6;
    const int wr = wid >> 1, wc = wid & 1;      // wave quadrant
    const int m  = lane & 15, kb = lane >> 4;   // MFMA lane decomposition
    const int m0 = blockIdx.y * 128, n0 = blockIdx.x * 128;

    f32x4 acc[4][4];
#pragma unroll
    for (int i = 0; i < 4; ++i)
#pragma unroll
        for (int j = 0; j < 4; ++j) acc[i][j] = (f32x4){0.f,0.f,0.f,0.f};

    for (int k0 = 0; k0 < DIM; k0 += 64) {
        // stage: 1024 chunks of 8 bf16 per tile; 4 per thread per operand.
        bf16x8 a_st[4], b_st[4];
#pragma unroll
        for (int i = 0; i < 4; ++i) {
            int c = tid + i*256;
            int row = c >> 3, slot = c & 7;
            int gs = slot ^ (row & 7);          // pre-swizzled source slot
            a_st[i] = *(const bf16x8*)&A[(size_t)(m0+row)*DIM + k0 + gs*8];
            b_st[i] = *(const bf16x8*)&B[(size_t)(n0+row)*DIM + k0 + gs*8];
        }
        __syncthreads();   // prior iter's frag reads done
#pragma unroll
        for (int i = 0; i < 4; ++i) {
            int c = tid + i*256;
            int row = c >> 3, slot = c & 7;
            *(bf16x8*)&As[row*64 + slot*8] = a_st[i];
            *(bf16x8*)&Bs[row*64 + slot*8] = b_st[i];
        }
        __syncthreads();

        bf16x8 af[2][4], bfr[2][4];
#pragma unroll
        for (int t = 0; t < 2; ++t) {
            int sl = ((t*4 + kb) ^ (m & 7)) * 8;
#pragma unroll
            for (int f = 0; f < 4; ++f) {
                af[t][f]  = *(const bf16x8*)&As[(wr*64 + f*16 + m)*64 + sl];
                bfr[t][f] = *(const bf16x8*)&Bs[(wc*64 + f*16 + m)*64 + sl];
            }
        }
#pragma unroll
        for (int fm = 0; fm < 4; ++fm)
#pragma unroll
            for (int fn = 0; fn < 4; ++fn) {
                acc[fm][fn] = __builtin_amdgcn_mfma_f32_16x16x32_bf16(af[0][fm], bfr[0][fn], acc[fm][fn], 0, 0, 0);
                acc[fm][fn] = __builtin_amdgcn_mfma_f32_16x16x32_bf16(af[1][fm], bfr[1][fn], acc[fm][fn], 0, 0, 0);
            }
    }

    // D layout: row = kb*4+r (within 16-block), col = m
#pragma unroll
    for (int fm = 0; fm < 4; ++fm)
#pragma unroll
        for (int fn = 0; fn < 4; ++fn) {
            int col = n0 + wc*64 + fn*16 + m;
#pragma unroll
            for (int r = 0; r < 4; ++r) {
                int row = m0 + wr*64 + fm*16 + kb*4 + r;
                if (F32OUT)
                    ((float*)Cv)[(size_t)row*DIM + col] = acc[fm][fn][r];
                else
                    ((short*)Cv)[(size_t)row*DIM + col] = f2bf(acc[fm][fn][r]);
            }
        }
}

// ---------------------------------------------------------------------------
// Flash attention, bf16 MFMA, bf16 I/O (q/k/v/ctx in bf16 from workspace).
// Structure identical to R4-verified version; staging reads bf16 directly.
// ---------------------------------------------------------------------------
__global__ __launch_bounds__(256)
void flash_mfma(const short* __restrict__ Qb,
                const short* __restrict__ Kb,
                const short* __restrict__ Vb,
                short* __restrict__ Ctx)
{
    __shared__ short K_lds[64 * 72];       // [c][d] bf16
    __shared__ short Vt_lds[48 * 72];      // [d][c] bf16
    __shared__ short P_lds[4][16 * 72];    // per wave: [q][c] bf16

    const int qt  = blockIdx.x;
    const int h   = blockIdx.y;
    const int b   = blockIdx.z;
    const int tid = threadIdx.x;
    const int wid  = tid >> 6;
    const int lane = tid & 63;
    const int m  = lane & 15;
    const int kb = lane >> 4;

    const int q0 = qt * 64;
    const size_t base = (size_t)b * SEQ * DIM + (size_t)h * HD;
    const float scale = 0.14433756729740643f;  // 48^-0.5

    // zero K_lds pad cols 48..63 once (MFMA B-frags read them; staging doesn't write them)
    for (int i = tid; i < 64 * 16; i += 256) {
        int r = i >> 4, c = i & 15;
        K_lds[r * 72 + 48 + c] = 0;
    }

    // Q fragments (row = q0 + wid*16 + m), direct bf16 load
    bf16x8 qf[2];
#pragma unroll
    for (int t = 0; t < 2; ++t) {
        int d0 = t * 32 + kb * 8;
        bf16x8 q8 = {};
        if (d0 < 48)
            q8 = *(const bf16x8*)&Qb[base + (size_t)(q0 + wid*16 + m) * DIM + d0];
        qf[t] = q8;
    }

    float m_i[4], l_i[4];
    f32x4 o[3];
#pragma unroll
    for (int r = 0; r < 4; ++r) { m_i[r] = -1e30f; l_i[r] = 0.f; }
#pragma unroll
    for (int ds = 0; ds < 3; ++ds) o[ds] = (f32x4){0.f,0.f,0.f,0.f};

    for (int c0 = 0; c0 < SEQ; c0 += 64) {
        // stage K and V^T: 2*384 chunks of 8 bf16, 3 per thread
        bf16x8 st[3]; int strow[3], stdc[3]; bool isK[3];
#pragma unroll
        for (int i = 0; i < 3; ++i) {
            int c = tid + i * 256;          // 0..767
            bool k_side = (c < 384);
            int cc = k_side ? c : c - 384;
            int row = cc / 6, dc = cc - row * 6;
            isK[i] = k_side; strow[i] = row; stdc[i] = dc;
            const short* src = (k_side ? Kb : Vb) + base + (size_t)(c0 + row) * DIM + dc * 8;
            st[i] = *(const bf16x8*)src;
        }
        __syncthreads();   // prior tile's LDS reads complete
#pragma unroll
        for (int i = 0; i < 3; ++i) {
            if (isK[i]) {
                *(bf16x8*)&K_lds[strow[i]*72 + stdc[i]*8] = st[i];
            } else {
#pragma unroll
                for (int j = 0; j < 8; ++j)
                    Vt_lds[(stdc[i]*8 + j)*72 + strow[i]] = st[i][j];
            }
        }
        __syncthreads();

        // S = Q K^T
        f32x4 s[4];
#pragma unroll
        for (int cs = 0; cs < 4; ++cs) {
            f32x4 acc = (f32x4){0.f,0.f,0.f,0.f};
#pragma unroll
            for (int t = 0; t < 2; ++t) {
                bf16x8 kf = *(bf16x8*)&K_lds[(cs*16 + m)*72 + t*32 + kb*8];
                acc = __builtin_amdgcn_mfma_f32_16x16x32_bf16(qf[t], kf, acc, 0, 0, 0);
            }
            s[cs] = acc;
        }

        // online softmax (rows kb*4+r, cols cs*16+m)
        float mx[4], alpha[4], rs[4];
#pragma unroll
        for (int r = 0; r < 4; ++r) {
#pragma unroll
            for (int cs = 0; cs < 4; ++cs) s[cs][r] *= scale;
            mx[r] = fmaxf(fmaxf(s[0][r], s[1][r]), fmaxf(s[2][r], s[3][r]));
        }
#pragma unroll
        for (int off = 1; off < 16; off <<= 1)
#pragma unroll
            for (int r = 0; r < 4; ++r)
                mx[r] = fmaxf(mx[r], __shfl_xor(mx[r], off));
#pragma unroll
        for (int r = 0; r < 4; ++r) {
            float mn = fmaxf(m_i[r], mx[r]);
            alpha[r] = __expf(m_i[r] - mn);
            m_i[r] = mn;
            rs[r] = 0.f;
#pragma unroll
            for (int cs = 0; cs < 4; ++cs) {
                float p = __expf(s[cs][r] - mn);
                s[cs][r] = p;
                rs[r] += p;
            }
        }
#pragma unroll
        for (int off = 1; off < 16; off <<= 1)
#pragma unroll
            for (int r = 0; r < 4; ++r)
                rs[r] += __shfl_xor(rs[r], off);
#pragma unroll
        for (int r = 0; r < 4; ++r)
            l_i[r] = alpha[r] * l_i[r] + rs[r];

        // P -> LDS (bf16, transposed to A-layout source)
#pragma unroll
        for (int cs = 0; cs < 4; ++cs)
#pragma unroll
            for (int r = 0; r < 4; ++r)
                P_lds[wid][(kb*4 + r)*72 + cs*16 + m] = f2bf(s[cs][r]);

        // O = alpha*O + P V
#pragma unroll
        for (int ds = 0; ds < 3; ++ds)
#pragma unroll
            for (int r = 0; r < 4; ++r)
                o[ds][r] *= alpha[r];

        bf16x8 pf[2];
#pragma unroll
        for (int t = 0; t < 2; ++t)
            pf[t] = *(bf16x8*)&P_lds[wid][m*72 + t*32 + kb*8];
#pragma unroll
        for (int ds = 0; ds < 3; ++ds) {
#pragma unroll
            for (int t = 0; t < 2; ++t) {
                bf16x8 vf = *(bf16x8*)&Vt_lds[(ds*16 + m)*72 + t*32 + kb*8];
                o[ds] = __builtin_amdgcn_mfma_f32_16x16x32_bf16(pf[t], vf, o[ds], 0, 0, 0);
            }
        }
    }

    float inv[4];
#pragma unroll
    for (int r = 0; r < 4; ++r) inv[r] = 1.0f / l_i[r];
#pragma unroll
    for (int ds = 0; ds < 3; ++ds)
#pragma unroll
        for (int r = 0; r < 4; ++r)
            Ctx[base + (size_t)(q0 + wid*16 + kb*4 + r) * DIM + ds*16 + m] = f2bf(o[ds][r] * inv[r]);
}

extern "C" void kernel_launch(void* const* d_in, const int* in_sizes, int n_in,
                              void* d_out, int out_size, void* d_ws, size_t ws_size,
                              hipStream_t stream)
{
    const float* x  = (const float*)d_in[0];
    const float* Wq = (const float*)d_in[1];
    const float* Wk = (const float*)d_in[2];
    const float* Wv = (const float*)d_in[3];
    const float* Wo = (const float*)d_in[4];
    float* out = (float*)d_out;

    const size_t XN = (size_t)NROWS * DIM;   // 3,145,728
    const size_t WN = (size_t)DIM * DIM;     //   589,824

    short* xb   = (short*)d_ws;
    short* wqb  = xb  + XN;
    short* wkb  = wqb + WN;
    short* wvb  = wkb + WN;
    short* wob  = wvb + WN;
    short* qb   = wob + WN;
    short* kbuf = qb  + XN;
    short* vbuf = kbuf + XN;
    short* ctxb = vbuf + XN;                 // end ~36.2 MB

    cvt_bf16<<<1024, 256, 0, stream>>>(x, Wq, Wk, Wv, Wo, xb);

    dim3 g1(DIM/128, NROWS/128, 3);
    gemm_mfma<false><<<g1, 256, 0, stream>>>(xb, wqb, wkb, wvb, qb, kbuf, vbuf);

    dim3 g2(SEQ/64, NH, NB);
    flash_mfma<<<g2, 256, 0, stream>>>(qb, kbuf, vbuf, ctxb);

    dim3 g3(DIM/128, NROWS/128, 1);
    gemm_mfma<true><<<g3, 256, 0, stream>>>(ctxb, wob, wob, wob, out, out, out);
}

// Round 6
// 195.900 us; speedup vs baseline: 4.2786x; 1.3048x over previous
//
#include <hip/hip_runtime.h>
#include <cstdint>

#define DIM 768
#define SEQ 2048
#define NB 2
#define NH 16
#define HD 48
#define NROWS (NB*SEQ)   // 4096

typedef __attribute__((ext_vector_type(8))) short bf16x8;
typedef __attribute__((ext_vector_type(4))) float f32x4;
typedef __attribute__((ext_vector_type(16))) float f32x16;
typedef unsigned int u32;

__device__ __forceinline__ short f2bf(float f) {
    union { float f; uint32_t u; } v; v.f = f;
    uint32_t u = v.u;
    uint32_t r = (u + 0x7FFFu + ((u >> 16) & 1u)) >> 16;
    return (short)r;
}

// ---------------------------------------------------------------------------
// fp32 -> bf16 pre-convert (unchanged, verified R5)
// ---------------------------------------------------------------------------
__global__ __launch_bounds__(256)
void cvt_bf16(const float* __restrict__ x,  const float* __restrict__ wq,
              const float* __restrict__ wk, const float* __restrict__ wv,
              const float* __restrict__ wo, short* __restrict__ dst)
{
    const int XN4 = (NROWS*DIM)/4;
    const int WN4 = (DIM*DIM)/4;
    const int T4  = XN4 + 4*WN4;
    for (int i = blockIdx.x*blockDim.x + threadIdx.x; i < T4; i += gridDim.x*blockDim.x) {
        const float* src; int off;
        if (i < XN4) { src = x; off = i; }
        else {
            int j = i - XN4;
            int w = j / WN4, r = j - w*WN4;
            src = (w==0) ? wq : (w==1) ? wk : (w==2) ? wv : wo;
            off = r;
        }
        float4 v = *(const float4*)(src + (size_t)off*4);
        short4 s; s.x=f2bf(v.x); s.y=f2bf(v.y); s.z=f2bf(v.z); s.w=f2bf(v.w);
        *(short4*)(dst + (size_t)i*4) = s;
    }
}

// ---------------------------------------------------------------------------
// bf16 MFMA GEMM (unchanged, verified R5)
// ---------------------------------------------------------------------------
template<bool F32OUT>
__global__ __launch_bounds__(256)
void gemm_mfma(const short* __restrict__ A,
               const short* __restrict__ B0, const short* __restrict__ B1,
               const short* __restrict__ B2,
               void* __restrict__ C0v, void* __restrict__ C1v, void* __restrict__ C2v)
{
    const short* B = B0; void* Cv = C0v;
    if (blockIdx.z == 1) { B = B1; Cv = C1v; }
    else if (blockIdx.z == 2) { B = B2; Cv = C2v; }

    __shared__ short As[128*64];
    __shared__ short Bs[128*64];

    const int tid  = threadIdx.x;
    const int lane = tid & 63;
    const int wid  = tid >> 6;
    const int wr = wid >> 1, wc = wid & 1;
    const int m  = lane & 15, kb = lane >> 4;
    const int m0 = blockIdx.y * 128, n0 = blockIdx.x * 128;

    f32x4 acc[4][4];
#pragma unroll
    for (int i = 0; i < 4; ++i)
#pragma unroll
        for (int j = 0; j < 4; ++j) acc[i][j] = (f32x4){0.f,0.f,0.f,0.f};

    for (int k0 = 0; k0 < DIM; k0 += 64) {
        bf16x8 a_st[4], b_st[4];
#pragma unroll
        for (int i = 0; i < 4; ++i) {
            int c = tid + i*256;
            int row = c >> 3, slot = c & 7;
            int gs = slot ^ (row & 7);
            a_st[i] = *(const bf16x8*)&A[(size_t)(m0+row)*DIM + k0 + gs*8];
            b_st[i] = *(const bf16x8*)&B[(size_t)(n0+row)*DIM + k0 + gs*8];
        }
        __syncthreads();
#pragma unroll
        for (int i = 0; i < 4; ++i) {
            int c = tid + i*256;
            int row = c >> 3, slot = c & 7;
            *(bf16x8*)&As[row*64 + slot*8] = a_st[i];
            *(bf16x8*)&Bs[row*64 + slot*8] = b_st[i];
        }
        __syncthreads();

        bf16x8 af[2][4], bfr[2][4];
#pragma unroll
        for (int t = 0; t < 2; ++t) {
            int sl = ((t*4 + kb) ^ (m & 7)) * 8;
#pragma unroll
            for (int f = 0; f < 4; ++f) {
                af[t][f]  = *(const bf16x8*)&As[(wr*64 + f*16 + m)*64 + sl];
                bfr[t][f] = *(const bf16x8*)&Bs[(wc*64 + f*16 + m)*64 + sl];
            }
        }
#pragma unroll
        for (int fm = 0; fm < 4; ++fm)
#pragma unroll
            for (int fn = 0; fn < 4; ++fn) {
                acc[fm][fn] = __builtin_amdgcn_mfma_f32_16x16x32_bf16(af[0][fm], bfr[0][fn], acc[fm][fn], 0, 0, 0);
                acc[fm][fn] = __builtin_amdgcn_mfma_f32_16x16x32_bf16(af[1][fm], bfr[1][fn], acc[fm][fn], 0, 0, 0);
            }
    }

#pragma unroll
    for (int fm = 0; fm < 4; ++fm)
#pragma unroll
        for (int fn = 0; fn < 4; ++fn) {
            int col = n0 + wc*64 + fn*16 + m;
#pragma unroll
            for (int r = 0; r < 4; ++r) {
                int row = m0 + wr*64 + fm*16 + kb*4 + r;
                if (F32OUT)
                    ((float*)Cv)[(size_t)row*DIM + col] = acc[fm][fn][r];
                else
                    ((short*)Cv)[(size_t)row*DIM + col] = f2bf(acc[fm][fn][r]);
            }
        }
}

// ---------------------------------------------------------------------------
// Flash attention v2: 32x32 MFMA, swapped operands.
//   S^T = mfma(A=K, B=Q)  -> lane holds scores for ONE q (col=lane&31)
//   O^T = mfma(A=V^T, B=P^T) -> same lane=q alignment for m/l/alpha
// P stays in registers (pack pairs -> shfl_xor(32) half-swap -> B-frag).
// K_lds: [64][64] bf16, slot^=(row&7) XOR swizzle (conflict-free b128).
// Vt_lds: [64][68] bf16 (stride 68 -> 2-way-free b64 reads; row-wide
// conflict-free scalar stores). Rows 48..63 zeroed once (R3 lesson).
// Per 64-col KV tile: 3 QKT MFMAs (K=48 exact) + 8 PV MFMAs, 2 barriers.
// K/V global loads register-prefetched across the compute phase (T14).
// Defer-max rescale (T13, 8 nats); P truncation-packed with consistent l.
// ---------------------------------------------------------------------------
__global__ __launch_bounds__(256)
void flash2(const short* __restrict__ Qb, const short* __restrict__ Kb,
            const short* __restrict__ Vb, short* __restrict__ Ctx)
{
    __shared__ short K_lds[64*64];
    __shared__ short Vt_lds[64*68];

    const int tid  = threadIdx.x;
    const int wid  = tid >> 6, lane = tid & 63;
    const int r    = lane & 31, hi = lane >> 5;
    const size_t base = (size_t)blockIdx.z*SEQ*DIM + (size_t)blockIdx.y*HD;
    const int q0 = blockIdx.x*128 + wid*32;
    const float C2  = 0.20823688f;   // 48^-0.5 * log2(e)
    const float THR = 11.5f;         // defer-max threshold (~8 nats)

    // zero V^T pad rows d=48..63 (never written in loop; read by PV A-frags)
    for (int i = tid; i < 16*68; i += 256) Vt_lds[48*68 + i] = 0;

    // Q regs: lane r holds q = q0+r; hi selects 8-elem d-half per 16-slice
    bf16x8 qf[3];
#pragma unroll
    for (int s = 0; s < 3; ++s)
        qf[s] = *(const bf16x8*)&Qb[base + (size_t)(q0 + r)*DIM + s*16 + hi*8];

    f32x16 z16;
#pragma unroll
    for (int i = 0; i < 16; ++i) z16[i] = 0.f;

    f32x16 acc0 = z16, acc1 = z16;   // O^T d-tiles 0..31 / 32..47(+pad)
    float m_i = -1e30f, l_i = 0.f;

    // K staging geometry: 64 rows x 8 slots of 8 bf16; 2 chunks/thread.
    // Physical slot ps holds logical slot ps^(row&7); logical 6,7 read
    // d=48..63 (beyond head -> harmless in-workspace bytes, never consumed).
    const int row0 = tid >> 3,       ps0 = tid & 7;
    const int row1 = (tid+256) >> 3, ps1 = tid & 7;
    const int ls0 = ps0 ^ (row0 & 7), ls1 = ps1 ^ (row1 & 7);

    bf16x8 k0r, k1r; short vreg[12];
    k0r = *(const bf16x8*)&Kb[base + (size_t)row0*DIM + ls0*8];
    k1r = *(const bf16x8*)&Kb[base + (size_t)row1*DIM + ls1*8];
#pragma unroll
    for (int j = 0; j < 12; ++j)
        vreg[j] = Vb[base + (size_t)lane*DIM + wid*12 + j];

    for (int t = 0; t < SEQ/64; ++t) {
        __syncthreads();                       // prior tile's LDS reads done
        *(bf16x8*)&K_lds[row0*64 + ps0*8] = k0r;
        *(bf16x8*)&K_lds[row1*64 + ps1*8] = k1r;
#pragma unroll
        for (int j = 0; j < 12; ++j)
            Vt_lds[(wid*12 + j)*68 + lane] = vreg[j];
        __syncthreads();

        if (t + 1 < SEQ/64) {                  // prefetch next tile (T14)
            int c0 = (t+1)*64;
            k0r = *(const bf16x8*)&Kb[base + (size_t)(c0 + row0)*DIM + ls0*8];
            k1r = *(const bf16x8*)&Kb[base + (size_t)(c0 + row1)*DIM + ls1*8];
#pragma unroll
            for (int j = 0; j < 12; ++j)
                vreg[j] = Vb[base + (size_t)(c0 + lane)*DIM + wid*12 + j];
        }

        // S^T = K * Q^T : 2 c-tiles x 3 K=16 slices
        f32x16 sa[2];
#pragma unroll
        for (int ct = 0; ct < 2; ++ct) {
            f32x16 a = z16;
#pragma unroll
            for (int s = 0; s < 3; ++s) {
                int row = ct*32 + r;
                bf16x8 kf = *(const bf16x8*)&K_lds[row*64 + ((s*2+hi) ^ (row&7))*8];
                a = __builtin_amdgcn_mfma_f32_32x32x16_bf16(kf, qf[s], a, 0, 0, 0);
            }
            sa[ct] = a;
        }

        // online softmax, fully in-register (lane pair l, l^32 share q)
        float mx = -1e30f;
#pragma unroll
        for (int ct = 0; ct < 2; ++ct)
#pragma unroll
            for (int i = 0; i < 16; ++i) mx = fmaxf(mx, sa[ct][i]);
        mx = fmaxf(mx, __shfl_xor(mx, 32));
        mx *= C2;

        float mn = m_i;
        if (!__all(mx - m_i <= THR)) {         // T13 defer-max
            mn = fmaxf(m_i, mx);
            float al = exp2f(m_i - mn);
            l_i *= al;
#pragma unroll
            for (int i = 0; i < 16; ++i) { acc0[i] *= al; acc1[i] *= al; }
            m_i = mn;
        }

        // p = exp2(s*C2 - mn); truncate-pack to bf16 pairs; l from truncated
        float rs = 0.f;
        u32 w[2][8], sw[2][8];
#pragma unroll
        for (int ct = 0; ct < 2; ++ct)
#pragma unroll
            for (int k = 0; k < 8; ++k) {
                float p0 = exp2f(fmaf(sa[ct][2*k],   C2, -mn));
                float p1 = exp2f(fmaf(sa[ct][2*k+1], C2, -mn));
                u32 b0 = __float_as_uint(p0), b1 = __float_as_uint(p1);
                w[ct][k] = (b1 & 0xffff0000u) | (b0 >> 16);
                rs += __uint_as_float(b0 & 0xffff0000u) + __uint_as_float(b1 & 0xffff0000u);
            }
        rs += __shfl_xor(rs, 32);
        l_i += rs;
#pragma unroll
        for (int ct = 0; ct < 2; ++ct)
#pragma unroll
            for (int k = 0; k < 8; ++k) sw[ct][k] = (u32)__shfl_xor((int)w[ct][k], 32);

        // O^T += V^T * P^T : assemble P B-frags via half-swap selects
#pragma unroll
        for (int ct = 0; ct < 2; ++ct)
#pragma unroll
            for (int hf = 0; hf < 2; ++hf) {
                u32 f0 = hi ? sw[ct][4*hf+2] : w[ct][4*hf+0];
                u32 f1 = hi ? sw[ct][4*hf+3] : w[ct][4*hf+1];
                u32 f2 = hi ? w[ct][4*hf+2]  : sw[ct][4*hf+0];
                u32 f3 = hi ? w[ct][4*hf+3]  : sw[ct][4*hf+1];
                int4 pw = make_int4((int)f0, (int)f1, (int)f2, (int)f3);
                bf16x8 pb = __builtin_bit_cast(bf16x8, pw);
#pragma unroll
                for (int dt = 0; dt < 2; ++dt) {
                    int off = (dt*32 + r)*68 + ct*32 + hf*16 + hi*8;
                    short4 v0 = *(const short4*)&Vt_lds[off];
                    short4 v1 = *(const short4*)&Vt_lds[off + 4];
                    bf16x8 av = {v0.x, v0.y, v0.z, v0.w, v1.x, v1.y, v1.z, v1.w};
                    if (dt == 0) acc0 = __builtin_amdgcn_mfma_f32_32x32x16_bf16(av, pb, acc0, 0, 0, 0);
                    else         acc1 = __builtin_amdgcn_mfma_f32_32x32x16_bf16(av, pb, acc1, 0, 0, 0);
                }
            }
    }

    // epilogue: O^T regs -> ctx[q][d], lane owns q = q0+r
    float inv = 1.0f / l_i;
#pragma unroll
    for (int g = 0; g < 16; ++g) {
        int d = (g&3) + 8*(g>>2) + 4*hi;
        Ctx[base + (size_t)(q0 + r)*DIM + d] = f2bf(acc0[g] * inv);
    }
#pragma unroll
    for (int g = 0; g < 8; ++g) {
        int d = 32 + (g&3) + 8*(g>>2) + 4*hi;
        Ctx[base + (size_t)(q0 + r)*DIM + d] = f2bf(acc1[g] * inv);
    }
}

extern "C" void kernel_launch(void* const* d_in, const int* in_sizes, int n_in,
                              void* d_out, int out_size, void* d_ws, size_t ws_size,
                              hipStream_t stream)
{
    const float* x  = (const float*)d_in[0];
    const float* Wq = (const float*)d_in[1];
    const float* Wk = (const float*)d_in[2];
    const float* Wv = (const float*)d_in[3];
    const float* Wo = (const float*)d_in[4];
    float* out = (float*)d_out;

    const size_t XN = (size_t)NROWS * DIM;
    const size_t WN = (size_t)DIM * DIM;

    short* xb   = (short*)d_ws;
    short* wqb  = xb  + XN;
    short* wkb  = wqb + WN;
    short* wvb  = wkb + WN;
    short* wob  = wvb + WN;
    short* qb   = wob + WN;
    short* kbuf = qb  + XN;
    short* vbuf = kbuf + XN;
    short* ctxb = vbuf + XN;

    cvt_bf16<<<1024, 256, 0, stream>>>(x, Wq, Wk, Wv, Wo, xb);

    dim3 g1(DIM/128, NROWS/128, 3);
    gemm_mfma<false><<<g1, 256, 0, stream>>>(xb, wqb, wkb, wvb, qb, kbuf, vbuf);

    dim3 g2(SEQ/128, NH, NB);
    flash2<<<g2, 256, 0, stream>>>(qb, kbuf, vbuf, ctxb);

    dim3 g3(DIM/128, NROWS/128, 1);
    gemm_mfma<true><<<g3, 256, 0, stream>>>(ctxb, wob, wob, wob, out, out, out);
}